// Round 1
// baseline (189.593 us; speedup 1.0000x reference)
//
#include <hip/hip_runtime.h>
#include <hip/hip_bf16.h>
#include <math.h>

typedef unsigned short u16;
typedef unsigned int u32;
typedef __attribute__((ext_vector_type(4))) float f32x4;
typedef __attribute__((ext_vector_type(8))) short bf16x8;

#define DI __device__ __forceinline__

DI u16 f2b(float x){ __hip_bfloat16 h = __float2bfloat16(x); return *reinterpret_cast<u16*>(&h); }
DI float b2f(u16 u){ union { float f; u32 i; } v; v.i = ((u32)u) << 16; return v.f; }

// ------------------------------------------------------------------
// 1) weights -> bf16. WB = [Wq;Wk;Wv] (1536x512), WoB = Wo (512x512)
// ------------------------------------------------------------------
__global__ void k_cvt(const float* __restrict__ Wq, const float* __restrict__ Wk,
                      const float* __restrict__ Wv, const float* __restrict__ Wo,
                      u16* __restrict__ WB, u16* __restrict__ WoB){
  int i = blockIdx.x * 256 + threadIdx.x;          // grid 1024 -> 262144
  WB[i]          = f2b(Wq[i]);
  WB[262144 + i] = f2b(Wk[i]);
  WB[524288 + i] = f2b(Wv[i]);
  WoB[i]         = f2b(Wo[i]);
}

// ------------------------------------------------------------------
// 2) pooled[b][c] = mean_n x[b][c][n]   (one wave per row)
// ------------------------------------------------------------------
__global__ __launch_bounds__(256) void k_pooled(const float* __restrict__ x, float* __restrict__ pooled){
  int row  = blockIdx.x * 4 + (threadIdx.x >> 6);  // 0..4095
  int lane = threadIdx.x & 63;
  const float4* p = (const float4*)(x + ((size_t)row << 10));
  float4 v0 = p[lane], v1 = p[lane + 64], v2 = p[lane + 128], v3 = p[lane + 192];
  float s = (v0.x + v0.y + v0.z + v0.w) + (v1.x + v1.y + v1.z + v1.w)
          + (v2.x + v2.y + v2.z + v2.w) + (v3.x + v3.y + v3.z + v3.w);
  #pragma unroll
  for (int o = 32; o > 0; o >>= 1) s += __shfl_down(s, o, 64);
  if (lane == 0) pooled[row] = s * (1.0f / 1024.0f);
}

// ------------------------------------------------------------------
// 3) SE: h1 = relu(pooled@Wse1^T + b), cw = sigmoid(h1@Wse2^T + b)
// ------------------------------------------------------------------
__global__ __launch_bounds__(256) void k_se(const float* __restrict__ pooled,
    const float* __restrict__ Wse1, const float* __restrict__ bse1,
    const float* __restrict__ Wse2, const float* __restrict__ bse2,
    float* __restrict__ cw){
  __shared__ float pl[512];
  __shared__ float h1[32];
  int b = blockIdx.x, t = threadIdx.x;
  pl[t] = pooled[b * 512 + t];
  pl[t + 256] = pooled[b * 512 + t + 256];
  __syncthreads();
  if (t < 32){
    float acc = bse1[t];
    const float* w = Wse1 + t * 512;
    for (int c = 0; c < 512; c++) acc = fmaf(pl[c], w[c], acc);
    h1[t] = fmaxf(acc, 0.0f);
  }
  __syncthreads();
  for (int c = t; c < 512; c += 256){
    float acc = bse2[c];
    const float* w = Wse2 + c * 32;
    #pragma unroll
    for (int j = 0; j < 32; j++) acc = fmaf(h1[j], w[j], acc);
    cw[b * 512 + c] = 1.0f / (1.0f + expf(-acc));
  }
}

// ------------------------------------------------------------------
// 4) spatial gate: m[b][h][n] = sigmoid(sum_c x[b][c][n]*Wsp[h][c] + bsp[h])
//    f32 throughout (mask threshold at 0.5 is precision-critical)
// ------------------------------------------------------------------
__global__ __launch_bounds__(256) void k_sp(const float* __restrict__ x,
    const float* __restrict__ Wsp, const float* __restrict__ bsp, float* __restrict__ mbuf){
  __shared__ float wsh[4096];          // Wsp[h][c]
  __shared__ float part[4][512];       // [cq][h*64+px]
  int t = threadIdx.x;
  for (int i = t; i < 4096; i += 256) wsh[i] = Wsp[i];
  __syncthreads();
  int b = blockIdx.x >> 4, n0 = (blockIdx.x & 15) << 6;   // grid 128
  int px = t & 63, cq = t >> 6;
  const float* xp = x + ((size_t)b << 19) + ((size_t)(cq * 128) << 10) + n0 + px;
  float acc[8] = {0,0,0,0,0,0,0,0};
  for (int c = 0; c < 128; c++){
    float xv = xp[(size_t)c << 10];
    #pragma unroll
    for (int h = 0; h < 8; h++) acc[h] = fmaf(xv, wsh[(h << 9) + cq * 128 + c], acc[h]);
  }
  #pragma unroll
  for (int h = 0; h < 8; h++) part[cq][(h << 6) + px] = acc[h];
  __syncthreads();
  for (int i = t; i < 512; i += 256){
    int h = i >> 6, p = i & 63;
    float s = part[0][i] + part[1][i] + part[2][i] + part[3][i] + bsp[h];
    mbuf[(((size_t)(b * 8 + h)) << 10) + n0 + p] = 1.0f / (1.0f + expf(-s));
  }
}

// ------------------------------------------------------------------
// 5) adaptive pool 7x7, threshold >0.5, upsample -> maskN (B,8,N) in {0,1}
// ------------------------------------------------------------------
__global__ void k_mask(const float* __restrict__ mbuf, float* __restrict__ maskN){
  __shared__ float sm[1024];
  __shared__ float mg[49];
  int bh = blockIdx.x, t = threadIdx.x;   // 64 blocks x 64 threads
  const float* mp = mbuf + ((size_t)bh << 10);
  for (int i = t; i < 1024; i += 64) sm[i] = mp[i];
  __syncthreads();
  if (t < 49){
    int ci = t / 7, cj = t % 7;
    int r0 = (ci * 32) / 7, r1 = ((ci + 1) * 32 + 6) / 7;
    int c0 = (cj * 32) / 7, c1 = ((cj + 1) * 32 + 6) / 7;
    float acc = 0.0f;
    for (int cc = c0; cc < c1; cc++){
      float rs = 0.0f;
      for (int rr = r0; rr < r1; rr++) rs += sm[rr * 32 + cc];
      acc += rs / (float)(r1 - r0);
    }
    float v = acc / (float)(c1 - c0);
    mg[t] = (v > 0.5f) ? 1.0f : 0.0f;
  }
  __syncthreads();
  for (int i = t; i < 1024; i += 64){
    int r = i >> 5, c = i & 31;
    maskN[((size_t)bh << 10) + i] = mg[((r * 7) >> 5) * 7 + ((c * 7) >> 5)];
  }
}

// ------------------------------------------------------------------
// 6) xf[b][n][c] = bf16( x[b][c][n] * cw[b][c] )   (tile transpose)
// ------------------------------------------------------------------
typedef __attribute__((ext_vector_type(8))) unsigned short us8;
__global__ __launch_bounds__(256) void k_xf(const float* __restrict__ x,
    const float* __restrict__ cw, u16* __restrict__ xfB){
  __shared__ float tile[64][65];
  int bid = blockIdx.x;                       // grid 1024 = 8b * 8c * 16n
  int b = bid >> 7, c0 = ((bid >> 4) & 7) << 6, n0 = (bid & 15) << 6;
  int t = threadIdx.x;
  {
    int cl = t >> 2, nc = (t & 3) << 4;
    const float* xp = x + ((size_t)(b * 512 + c0 + cl) << 10) + n0 + nc;
    float cwv = cw[b * 512 + c0 + cl];
    #pragma unroll
    for (int i = 0; i < 16; i += 4){
      float4 v = *(const float4*)(xp + i);
      tile[cl][nc + i + 0] = v.x * cwv;
      tile[cl][nc + i + 1] = v.y * cwv;
      tile[cl][nc + i + 2] = v.z * cwv;
      tile[cl][nc + i + 3] = v.w * cwv;
    }
  }
  __syncthreads();
  {
    int nl = t >> 2, cc = (t & 3) << 4;
    u16* op = xfB + ((size_t)(b * 1024 + n0 + nl) << 9) + c0 + cc;
    us8 o0, o1;
    #pragma unroll
    for (int i = 0; i < 8; i++)  o0[i] = f2b(tile[cc + i][nl]);
    #pragma unroll
    for (int i = 0; i < 8; i++)  o1[i] = f2b(tile[cc + 8 + i][nl]);
    *(us8*)op = o0;
    *(us8*)(op + 8) = o1;
  }
}

// ------------------------------------------------------------------
// 7/9) bf16 MFMA GEMM: Out[m][o] = sum_k A[m][k]*W[o][k] + bias
//   128x128 block tile, 4 waves (64x64 each), BK=32, K=512
//   MODE 0: W=[Wq;Wk;Wv] (1536 cols), scatter to Q/K/V (B,h,N,d) bf16
//   MODE 1: W=Wo (512 cols), write attnO (B,N,C) f32
// ------------------------------------------------------------------
template<int MODE>
__global__ __launch_bounds__(256) void k_gemm(const u16* __restrict__ A, const u16* __restrict__ Bw,
    const float* __restrict__ b0, const float* __restrict__ b1, const float* __restrict__ b2,
    u16* __restrict__ outQ, u16* __restrict__ outK, u16* __restrict__ outV, float* __restrict__ outF){
  __shared__ u16 As[128 * 40];
  __shared__ u16 Bs[128 * 40];
  int m0 = blockIdx.x * 128, n0 = blockIdx.y * 128;
  int t = threadIdx.x, lane = t & 63, w = t >> 6;
  int wr = w >> 1, wc = w & 1;
  f32x4 acc[4][4];
  #pragma unroll
  for (int mt = 0; mt < 4; mt++)
    #pragma unroll
    for (int nt = 0; nt < 4; nt++) acc[mt][nt] = (f32x4){0.f, 0.f, 0.f, 0.f};

  int srow = t >> 1, scol = (t & 1) << 4;
  const u16* ap = A  + (size_t)(m0 + srow) * 512 + scol;
  const u16* bp = Bw + (size_t)(n0 + srow) * 512 + scol;

  for (int k0 = 0; k0 < 512; k0 += 32){
    uint4 av0 = *(const uint4*)(ap + k0);
    uint4 av1 = *(const uint4*)(ap + k0 + 8);
    uint4 bv0 = *(const uint4*)(bp + k0);
    uint4 bv1 = *(const uint4*)(bp + k0 + 8);
    *(uint4*)&As[srow * 40 + scol]     = av0;
    *(uint4*)&As[srow * 40 + scol + 8] = av1;
    *(uint4*)&Bs[srow * 40 + scol]     = bv0;
    *(uint4*)&Bs[srow * 40 + scol + 8] = bv1;
    __syncthreads();
    bf16x8 afr[4], bfr[4];
    #pragma unroll
    for (int mt = 0; mt < 4; mt++)
      afr[mt] = *(bf16x8*)&As[(wr * 64 + mt * 16 + (lane & 15)) * 40 + ((lane >> 4) << 3)];
    #pragma unroll
    for (int nt = 0; nt < 4; nt++)
      bfr[nt] = *(bf16x8*)&Bs[(wc * 64 + nt * 16 + (lane & 15)) * 40 + ((lane >> 4) << 3)];
    #pragma unroll
    for (int mt = 0; mt < 4; mt++)
      #pragma unroll
      for (int nt = 0; nt < 4; nt++)
        acc[mt][nt] = __builtin_amdgcn_mfma_f32_16x16x32_bf16(afr[mt], bfr[nt], acc[mt][nt], 0, 0, 0);
    __syncthreads();
  }

  #pragma unroll
  for (int mt = 0; mt < 4; mt++){
    #pragma unroll
    for (int nt = 0; nt < 4; nt++){
      int o = n0 + wc * 64 + nt * 16 + (lane & 15);
      if (MODE == 0){
        int which = o >> 9, c = o & 511;
        float bias = (which == 0) ? b0[c] : (which == 1) ? b1[c] : b2[c];
        u16* base = (which == 0) ? outQ : (which == 1) ? outK : outV;
        int h = c >> 6, d = c & 63;
        #pragma unroll
        for (int j = 0; j < 4; j++){
          int m = m0 + wr * 64 + mt * 16 + ((lane >> 4) << 2) + j;
          int b = m >> 10, n = m & 1023;
          base[(((size_t)(b * 8 + h)) << 16) + ((size_t)n << 6) + d] = f2b(acc[mt][nt][j] + bias);
        }
      } else {
        float bias = b0[o];
        #pragma unroll
        for (int j = 0; j < 4; j++){
          int m = m0 + wr * 64 + mt * 16 + ((lane >> 4) << 2) + j;
          outF[((size_t)m << 9) + o] = acc[mt][nt][j] + bias;
        }
      }
    }
  }
}

// ------------------------------------------------------------------
// 8) flash attention per (b,h): 64 q-rows per block, 16 K/V tiles of 64
// ------------------------------------------------------------------
__global__ __launch_bounds__(256) void k_flash(const u16* __restrict__ Q, const u16* __restrict__ K,
    const u16* __restrict__ V, const float* __restrict__ maskN, u16* __restrict__ attnB){
  __shared__ u16 Qs[64 * 72];
  __shared__ u16 Ks[64 * 72];
  __shared__ u16 Vts[64 * 72];
  __shared__ float mks[64];
  __shared__ u16 Ps[4][16 * 72];
  int bid = blockIdx.x;                          // 1024 = bh*16 + qt
  int bh = bid >> 4, q0 = (bid & 15) << 6;
  int t = threadIdx.x, lane = t & 63, w = t >> 6;
  const u16* Qp = Q + ((size_t)bh << 16) + ((size_t)q0 << 6);
  const u16* Kp = K + ((size_t)bh << 16);
  const u16* Vp = V + ((size_t)bh << 16);
  const float* mkp = maskN + ((size_t)bh << 10);

  { // stage Q (each wave stages & later reads its own 16 rows)
    int r = t >> 2, c = (t & 3) << 4;
    uint4 v0 = *(const uint4*)(Qp + (r << 6) + c);
    uint4 v1 = *(const uint4*)(Qp + (r << 6) + c + 8);
    *(uint4*)&Qs[r * 72 + c] = v0;
    *(uint4*)&Qs[r * 72 + c + 8] = v1;
  }
  float mq[4];
  #pragma unroll
  for (int j = 0; j < 4; j++) mq[j] = mkp[q0 + w * 16 + ((lane >> 4) << 2) + j];

  f32x4 oacc[4];
  float mrun[4], lrun[4];
  #pragma unroll
  for (int j = 0; j < 4; j++){ mrun[j] = -INFINITY; lrun[j] = 0.0f; }
  #pragma unroll
  for (int dt = 0; dt < 4; dt++) oacc[dt] = (f32x4){0.f, 0.f, 0.f, 0.f};

  for (int kt = 0; kt < 16; kt++){
    __syncthreads();
    { // stage K, V^T, mask
      int r = t >> 2, c = (t & 3) << 4;
      const u16* ks = Kp + (((size_t)(kt * 64 + r)) << 6) + c;
      uint4 k0v = *(const uint4*)ks;
      uint4 k1v = *(const uint4*)(ks + 8);
      *(uint4*)&Ks[r * 72 + c] = k0v;
      *(uint4*)&Ks[r * 72 + c + 8] = k1v;
      const u16* vs = Vp + (((size_t)(kt * 64 + r)) << 6) + c;
      union { uint4 v[2]; u16 u[16]; } tv;
      tv.v[0] = *(const uint4*)vs;
      tv.v[1] = *(const uint4*)(vs + 8);
      #pragma unroll
      for (int i = 0; i < 16; i++) Vts[(c + i) * 72 + r] = tv.u[i];
      if (t < 64) mks[t] = mkp[kt * 64 + t];
    }
    __syncthreads();

    // S = Q K^T (wave's 16 q-rows x 64 keys)
    f32x4 sacc[4];
    #pragma unroll
    for (int n2 = 0; n2 < 4; n2++) sacc[n2] = (f32x4){0.f, 0.f, 0.f, 0.f};
    #pragma unroll
    for (int kc = 0; kc < 2; kc++){
      bf16x8 aq = *(bf16x8*)&Qs[(w * 16 + (lane & 15)) * 72 + kc * 32 + ((lane >> 4) << 3)];
      #pragma unroll
      for (int n2 = 0; n2 < 4; n2++){
        bf16x8 bk = *(bf16x8*)&Ks[(n2 * 16 + (lane & 15)) * 72 + kc * 32 + ((lane >> 4) << 3)];
        sacc[n2] = __builtin_amdgcn_mfma_f32_16x16x32_bf16(aq, bk, sacc[n2], 0, 0, 0);
      }
    }

    float mk4[4];
    #pragma unroll
    for (int n2 = 0; n2 < 4; n2++) mk4[n2] = mks[n2 * 16 + (lane & 15)];

    float tmax[4] = {-INFINITY, -INFINITY, -INFINITY, -INFINITY};
    #pragma unroll
    for (int n2 = 0; n2 < 4; n2++)
      #pragma unroll
      for (int j = 0; j < 4; j++){
        float s = sacc[n2][j] * 0.125f + (1.0f - mq[j] * mk4[n2]) * (-1e9f);
        sacc[n2][j] = s;
        tmax[j] = fmaxf(tmax[j], s);
      }
    #pragma unroll
    for (int o = 1; o < 16; o <<= 1)
      #pragma unroll
      for (int j = 0; j < 4; j++) tmax[j] = fmaxf(tmax[j], __shfl_xor(tmax[j], o, 64));

    float scl[4], rsum[4];
    #pragma unroll
    for (int j = 0; j < 4; j++){
      float mn = fmaxf(mrun[j], tmax[j]);
      scl[j] = __expf(mrun[j] - mn);
      mrun[j] = mn;
      rsum[j] = 0.0f;
    }
    #pragma unroll
    for (int n2 = 0; n2 < 4; n2++)
      #pragma unroll
      for (int j = 0; j < 4; j++){
        float p = __expf(sacc[n2][j] - mrun[j]);
        sacc[n2][j] = p;
        rsum[j] += p;
      }
    #pragma unroll
    for (int o = 1; o < 16; o <<= 1)
      #pragma unroll
      for (int j = 0; j < 4; j++) rsum[j] += __shfl_xor(rsum[j], o, 64);
    #pragma unroll
    for (int j = 0; j < 4; j++) lrun[j] = lrun[j] * scl[j] + rsum[j];
    #pragma unroll
    for (int dt = 0; dt < 4; dt++)
      #pragma unroll
      for (int j = 0; j < 4; j++) oacc[dt][j] *= scl[j];

    // P -> LDS (per-wave region), then PV
    #pragma unroll
    for (int n2 = 0; n2 < 4; n2++)
      #pragma unroll
      for (int j = 0; j < 4; j++)
        Ps[w][(((lane >> 4) << 2) + j) * 72 + n2 * 16 + (lane & 15)] = f2b(sacc[n2][j]);

    #pragma unroll
    for (int kc = 0; kc < 2; kc++){
      bf16x8 apf = *(bf16x8*)&Ps[w][(lane & 15) * 72 + kc * 32 + ((lane >> 4) << 3)];
      #pragma unroll
      for (int dt = 0; dt < 4; dt++){
        bf16x8 bvf = *(bf16x8*)&Vts[(dt * 16 + (lane & 15)) * 72 + kc * 32 + ((lane >> 4) << 3)];
        oacc[dt] = __builtin_amdgcn_mfma_f32_16x16x32_bf16(apf, bvf, oacc[dt], 0, 0, 0);
      }
    }
  }

  int b = bh >> 3, h = bh & 7;
  #pragma unroll
  for (int dt = 0; dt < 4; dt++)
    #pragma unroll
    for (int j = 0; j < 4; j++){
      int q = q0 + w * 16 + ((lane >> 4) << 2) + j;
      int d = dt * 16 + (lane & 15);
      attnB[((size_t)(b * 1024 + q) << 9) + h * 64 + d] = f2b(oacc[dt][j] / lrun[j]);
    }
}

// ------------------------------------------------------------------
// 10) LN over C + transpose to (B,C,N)
// ------------------------------------------------------------------
__global__ __launch_bounds__(256) void k_ln(const u16* __restrict__ xfB, const float* __restrict__ attnO,
    const float* __restrict__ gamma, const float* __restrict__ beta, float* __restrict__ out){
  __shared__ float mu_s[64], rs_s[64];
  __shared__ float tile[64][65];
  int b = blockIdx.x >> 4, n0 = (blockIdx.x & 15) << 6;   // grid 128
  int t = threadIdx.x, w = t >> 6, lane = t & 63;

  for (int r = w * 16; r < w * 16 + 16; r++){
    size_t rb = ((size_t)(b * 1024 + n0 + r)) << 9;
    const float* ap = attnO + rb + lane * 8;
    const u16*  xp = xfB + rb + lane * 8;
    float4 a0 = *(const float4*)ap;
    float4 a1 = *(const float4*)(ap + 4);
    union { uint4 v; u16 u[8]; } xv; xv.v = *(const uint4*)xp;
    float v0 = a0.x + b2f(xv.u[0]), v1 = a0.y + b2f(xv.u[1]);
    float v2 = a0.z + b2f(xv.u[2]), v3 = a0.w + b2f(xv.u[3]);
    float v4 = a1.x + b2f(xv.u[4]), v5 = a1.y + b2f(xv.u[5]);
    float v6 = a1.z + b2f(xv.u[6]), v7 = a1.w + b2f(xv.u[7]);
    float s  = v0 + v1 + v2 + v3 + v4 + v5 + v6 + v7;
    float s2 = v0*v0 + v1*v1 + v2*v2 + v3*v3 + v4*v4 + v5*v5 + v6*v6 + v7*v7;
    #pragma unroll
    for (int o = 32; o > 0; o >>= 1){ s += __shfl_xor(s, o, 64); s2 += __shfl_xor(s2, o, 64); }
    if (lane == 0){
      float mu = s * (1.0f / 512.0f);
      float var = s2 * (1.0f / 512.0f) - mu * mu;
      mu_s[r] = mu;
      rs_s[r] = 1.0f / sqrtf(var + 1e-5f);
    }
  }
  __syncthreads();

  for (int ch = 0; ch < 8; ch++){
    int c0 = ch * 64;
    {
      int r = t >> 2, cp = (t & 3) << 4;
      size_t rb = (((size_t)(b * 1024 + n0 + r)) << 9) + c0 + cp;
      float mu = mu_s[r], rstd = rs_s[r];
      #pragma unroll
      for (int i2 = 0; i2 < 2; i2++){
        float4 a0 = *(const float4*)(attnO + rb + i2 * 8);
        float4 a1 = *(const float4*)(attnO + rb + i2 * 8 + 4);
        union { uint4 v; u16 u[8]; } xv; xv.v = *(const uint4*)(xfB + rb + i2 * 8);
        float vv[8] = { a0.x + b2f(xv.u[0]), a0.y + b2f(xv.u[1]), a0.z + b2f(xv.u[2]), a0.w + b2f(xv.u[3]),
                        a1.x + b2f(xv.u[4]), a1.y + b2f(xv.u[5]), a1.z + b2f(xv.u[6]), a1.w + b2f(xv.u[7]) };
        #pragma unroll
        for (int i = 0; i < 8; i++){
          int c = c0 + cp + i2 * 8 + i;
          tile[r][cp + i2 * 8 + i] = (vv[i] - mu) * rstd * gamma[c] + beta[c];
        }
      }
    }
    __syncthreads();
    {
      int cl = t >> 2, np_ = (t & 3) << 4;
      float* op = out + (((size_t)(b * 512 + c0 + cl)) << 10) + n0 + np_;
      #pragma unroll
      for (int i = 0; i < 16; i += 4){
        float4 vo = { tile[np_ + i][cl], tile[np_ + i + 1][cl], tile[np_ + i + 2][cl], tile[np_ + i + 3][cl] };
        *(float4*)(op + i) = vo;
      }
    }
    __syncthreads();
  }
}

// ------------------------------------------------------------------
extern "C" void kernel_launch(void* const* d_in, const int* in_sizes, int n_in,
                              void* d_out, int out_size, void* d_ws, size_t ws_size,
                              hipStream_t stream){
  (void)in_sizes; (void)n_in; (void)out_size; (void)ws_size;
  const float* x    = (const float*)d_in[0];
  const float* Wq   = (const float*)d_in[1];
  const float* bq   = (const float*)d_in[2];
  const float* Wk   = (const float*)d_in[3];
  const float* bk   = (const float*)d_in[4];
  const float* Wv   = (const float*)d_in[5];
  const float* bv   = (const float*)d_in[6];
  const float* Wo   = (const float*)d_in[7];
  const float* bo   = (const float*)d_in[8];
  const float* Wsp  = (const float*)d_in[9];
  const float* bsp  = (const float*)d_in[10];
  const float* Wse1 = (const float*)d_in[11];
  const float* bse1 = (const float*)d_in[12];
  const float* Wse2 = (const float*)d_in[13];
  const float* bse2 = (const float*)d_in[14];
  const float* gamma= (const float*)d_in[15];
  const float* beta = (const float*)d_in[16];
  float* out = (float*)d_out;

  char* ws = (char*)d_ws;
  size_t off = 0;
  auto alloc = [&](size_t bytes) -> void* {
    void* p = ws + off;
    off += (bytes + 255) & ~(size_t)255;
    return p;
  };
  u16*   WB     = (u16*)  alloc(1536 * 512 * 2);
  u16*   WoB    = (u16*)  alloc(512 * 512 * 2);
  float* pooled = (float*)alloc(4096 * 4);
  float* cw     = (float*)alloc(4096 * 4);
  float* mbuf   = (float*)alloc(65536 * 4);
  float* maskN  = (float*)alloc(65536 * 4);
  u16*   xfB    = (u16*)  alloc((size_t)8192 * 512 * 2);
  u16*   Qb     = (u16*)  alloc(8388608);
  u16*   Kb     = (u16*)  alloc(8388608);
  u16*   Vb     = (u16*)  alloc(8388608);
  u16*   attnB  = (u16*)  alloc(8388608);
  float* attnO  = (float*)Qb;   // alias Q+K (16.78MB) after flash is done

  k_cvt   <<<dim3(1024), dim3(256), 0, stream>>>(Wq, Wk, Wv, Wo, WB, WoB);
  k_pooled<<<dim3(1024), dim3(256), 0, stream>>>(x, pooled);
  k_se    <<<dim3(8),    dim3(256), 0, stream>>>(pooled, Wse1, bse1, Wse2, bse2, cw);
  k_sp    <<<dim3(128),  dim3(256), 0, stream>>>(x, Wsp, bsp, mbuf);
  k_mask  <<<dim3(64),   dim3(64),  0, stream>>>(mbuf, maskN);
  k_xf    <<<dim3(1024), dim3(256), 0, stream>>>(x, cw, xfB);
  k_gemm<0><<<dim3(64, 12), dim3(256), 0, stream>>>(xfB, WB, bq, bk, bv, Qb, Kb, Vb, (float*)nullptr);
  k_flash <<<dim3(1024), dim3(256), 0, stream>>>(Qb, Kb, Vb, maskN, attnB);
  k_gemm<1><<<dim3(64, 4), dim3(256), 0, stream>>>(attnB, WoB, bo, bo, bo, nullptr, nullptr, nullptr, attnO);
  k_ln    <<<dim3(128),  dim3(256), 0, stream>>>(xfB, attnO, gamma, beta, out);
}

// Round 2
// 156.490 us; speedup vs baseline: 1.2115x; 1.2115x over previous
//
#include <hip/hip_runtime.h>
#include <hip/hip_bf16.h>
#include <math.h>

typedef unsigned short u16;
typedef unsigned int u32;
typedef __attribute__((ext_vector_type(4))) float f32x4;
typedef __attribute__((ext_vector_type(8))) short bf16x8;
typedef __attribute__((ext_vector_type(4))) unsigned short us4;
typedef __attribute__((ext_vector_type(8))) unsigned short us8;

#define DI __device__ __forceinline__

DI u16 f2b(float x){ __hip_bfloat16 h = __float2bfloat16(x); return *reinterpret_cast<u16*>(&h); }
DI float b2f(u16 u){ union { float f; u32 i; } v; v.i = ((u32)u) << 16; return v.f; }

// ------------------------------------------------------------------
// 1) weights -> bf16. WB = [Wq;Wk;Wv] (1536x512), WoB = Wo (512x512)
// ------------------------------------------------------------------
__global__ void k_cvt(const float* __restrict__ Wq, const float* __restrict__ Wk,
                      const float* __restrict__ Wv, const float* __restrict__ Wo,
                      u16* __restrict__ WB, u16* __restrict__ WoB){
  int i = blockIdx.x * 256 + threadIdx.x;          // grid 1024 -> 262144
  WB[i]          = f2b(Wq[i]);
  WB[262144 + i] = f2b(Wk[i]);
  WB[524288 + i] = f2b(Wv[i]);
  WoB[i]         = f2b(Wo[i]);
}

// ------------------------------------------------------------------
// 2) pooled[b][c] = mean_n x[b][c][n]   (one wave per row)
// ------------------------------------------------------------------
__global__ __launch_bounds__(256) void k_pooled(const float* __restrict__ x, float* __restrict__ pooled){
  int row  = blockIdx.x * 4 + (threadIdx.x >> 6);  // 0..4095
  int lane = threadIdx.x & 63;
  const float4* p = (const float4*)(x + ((size_t)row << 10));
  float4 v0 = p[lane], v1 = p[lane + 64], v2 = p[lane + 128], v3 = p[lane + 192];
  float s = (v0.x + v0.y + v0.z + v0.w) + (v1.x + v1.y + v1.z + v1.w)
          + (v2.x + v2.y + v2.z + v2.w) + (v3.x + v3.y + v3.z + v3.w);
  #pragma unroll
  for (int o = 32; o > 0; o >>= 1) s += __shfl_down(s, o, 64);
  if (lane == 0) pooled[row] = s * (1.0f / 1024.0f);
}

// ------------------------------------------------------------------
// 3) SE: h1 = relu(pooled@Wse1^T + b), cw = sigmoid(h1@Wse2^T + b)
// ------------------------------------------------------------------
__global__ __launch_bounds__(256) void k_se(const float* __restrict__ pooled,
    const float* __restrict__ Wse1, const float* __restrict__ bse1,
    const float* __restrict__ Wse2, const float* __restrict__ bse2,
    float* __restrict__ cw){
  __shared__ float pl[512];
  __shared__ float h1[32];
  int b = blockIdx.x, t = threadIdx.x;
  pl[t] = pooled[b * 512 + t];
  pl[t + 256] = pooled[b * 512 + t + 256];
  __syncthreads();
  if (t < 32){
    float acc = bse1[t];
    const float* w = Wse1 + t * 512;
    for (int c = 0; c < 512; c++) acc = fmaf(pl[c], w[c], acc);
    h1[t] = fmaxf(acc, 0.0f);
  }
  __syncthreads();
  for (int c = t; c < 512; c += 256){
    float acc = bse2[c];
    const float* w = Wse2 + c * 32;
    #pragma unroll
    for (int j = 0; j < 32; j++) acc = fmaf(h1[j], w[j], acc);
    cw[b * 512 + c] = 1.0f / (1.0f + expf(-acc));
  }
}

// ------------------------------------------------------------------
// 4) spatial gate: m[b][h][n] = sigmoid(sum_c x[b][c][n]*Wsp[h][c] + bsp[h])
// ------------------------------------------------------------------
__global__ __launch_bounds__(256) void k_sp(const float* __restrict__ x,
    const float* __restrict__ Wsp, const float* __restrict__ bsp, float* __restrict__ mbuf){
  __shared__ float wsh[4096];          // Wsp[h][c]
  __shared__ float part[4][512];       // [cq][h*64+px]
  int t = threadIdx.x;
  for (int i = t; i < 4096; i += 256) wsh[i] = Wsp[i];
  __syncthreads();
  int b = blockIdx.x >> 4, n0 = (blockIdx.x & 15) << 6;   // grid 128
  int px = t & 63, cq = t >> 6;
  const float* xp = x + ((size_t)b << 19) + ((size_t)(cq * 128) << 10) + n0 + px;
  float acc[8] = {0,0,0,0,0,0,0,0};
  for (int c = 0; c < 128; c++){
    float xv = xp[(size_t)c << 10];
    #pragma unroll
    for (int h = 0; h < 8; h++) acc[h] = fmaf(xv, wsh[(h << 9) + cq * 128 + c], acc[h]);
  }
  #pragma unroll
  for (int h = 0; h < 8; h++) part[cq][(h << 6) + px] = acc[h];
  __syncthreads();
  for (int i = t; i < 512; i += 256){
    int h = i >> 6, p = i & 63;
    float s = part[0][i] + part[1][i] + part[2][i] + part[3][i] + bsp[h];
    mbuf[(((size_t)(b * 8 + h)) << 10) + n0 + p] = 1.0f / (1.0f + expf(-s));
  }
}

// ------------------------------------------------------------------
// 5) adaptive pool 7x7, threshold, upsample -> bneg (B,8,N) in {0,-1e9}
// ------------------------------------------------------------------
__global__ void k_mask(const float* __restrict__ mbuf, float* __restrict__ bneg){
  __shared__ float sm[1024];
  __shared__ float mg[49];
  int bh = blockIdx.x, t = threadIdx.x;   // 64 blocks x 64 threads
  const float* mp = mbuf + ((size_t)bh << 10);
  for (int i = t; i < 1024; i += 64) sm[i] = mp[i];
  __syncthreads();
  if (t < 49){
    int ci = t / 7, cj = t % 7;
    int r0 = (ci * 32) / 7, r1 = ((ci + 1) * 32 + 6) / 7;
    int c0 = (cj * 32) / 7, c1 = ((cj + 1) * 32 + 6) / 7;
    float acc = 0.0f;
    for (int cc = c0; cc < c1; cc++){
      float rs = 0.0f;
      for (int rr = r0; rr < r1; rr++) rs += sm[rr * 32 + cc];
      acc += rs / (float)(r1 - r0);
    }
    float v = acc / (float)(c1 - c0);
    mg[t] = (v > 0.5f) ? 1.0f : 0.0f;
  }
  __syncthreads();
  for (int i = t; i < 1024; i += 64){
    int r = i >> 5, c = i & 31;
    float m = mg[((r * 7) >> 5) * 7 + ((c * 7) >> 5)];
    bneg[((size_t)bh << 10) + i] = (m > 0.5f) ? 0.0f : -1e9f;
  }
}

// ------------------------------------------------------------------
// 6) xf[b][n][c] = bf16( x[b][c][n] * cw[b][c] )   (tile transpose)
// ------------------------------------------------------------------
__global__ __launch_bounds__(256) void k_xf(const float* __restrict__ x,
    const float* __restrict__ cw, u16* __restrict__ xfB){
  __shared__ float tile[64][65];
  int bid = blockIdx.x;                       // grid 1024 = 8b * 8c * 16n
  int b = bid >> 7, c0 = ((bid >> 4) & 7) << 6, n0 = (bid & 15) << 6;
  int t = threadIdx.x;
  {
    int cl = t >> 2, nc = (t & 3) << 4;
    const float* xp = x + ((size_t)(b * 512 + c0 + cl) << 10) + n0 + nc;
    float cwv = cw[b * 512 + c0 + cl];
    #pragma unroll
    for (int i = 0; i < 16; i += 4){
      float4 v = *(const float4*)(xp + i);
      tile[cl][nc + i + 0] = v.x * cwv;
      tile[cl][nc + i + 1] = v.y * cwv;
      tile[cl][nc + i + 2] = v.z * cwv;
      tile[cl][nc + i + 3] = v.w * cwv;
    }
  }
  __syncthreads();
  {
    int nl = t >> 2, cc = (t & 3) << 4;
    u16* op = xfB + ((size_t)(b * 1024 + n0 + nl) << 9) + c0 + cc;
    us8 o0, o1;
    #pragma unroll
    for (int i = 0; i < 8; i++)  o0[i] = f2b(tile[cc + i][nl]);
    #pragma unroll
    for (int i = 0; i < 8; i++)  o1[i] = f2b(tile[cc + 8 + i][nl]);
    *(us8*)op = o0;
    *(us8*)(op + 8) = o1;
  }
}

// ------------------------------------------------------------------
// 7/9) bf16 MFMA GEMM: Out[m][o] = sum_k A[m][k]*W[o][k] + bias
//   MODE 0: W=[Wq;Wk;Wv]; Q,K -> (B,h,N,d) bf16; V -> Vt (B,h,d,N') bf16
//           where N' is slot-permuted within 32-blocks to feed flash PV.
//   MODE 1: W=Wo, write attnO (B,N,C) f32
// ------------------------------------------------------------------
template<int MODE>
__global__ __launch_bounds__(256) void k_gemm(const u16* __restrict__ A, const u16* __restrict__ Bw,
    const float* __restrict__ b0, const float* __restrict__ b1, const float* __restrict__ b2,
    u16* __restrict__ outQ, u16* __restrict__ outK, u16* __restrict__ outV, float* __restrict__ outF){
  __shared__ u16 As[128 * 40];
  __shared__ u16 Bs[128 * 40];
  int m0 = blockIdx.x * 128, n0 = blockIdx.y * 128;
  int t = threadIdx.x, lane = t & 63, w = t >> 6;
  int wr = w >> 1, wc = w & 1;
  f32x4 acc[4][4];
  #pragma unroll
  for (int mt = 0; mt < 4; mt++)
    #pragma unroll
    for (int nt = 0; nt < 4; nt++) acc[mt][nt] = (f32x4){0.f, 0.f, 0.f, 0.f};

  int srow = t >> 1, scol = (t & 1) << 4;
  const u16* ap = A  + (size_t)(m0 + srow) * 512 + scol;
  const u16* bp = Bw + (size_t)(n0 + srow) * 512 + scol;

  for (int k0 = 0; k0 < 512; k0 += 32){
    uint4 av0 = *(const uint4*)(ap + k0);
    uint4 av1 = *(const uint4*)(ap + k0 + 8);
    uint4 bv0 = *(const uint4*)(bp + k0);
    uint4 bv1 = *(const uint4*)(bp + k0 + 8);
    *(uint4*)&As[srow * 40 + scol]     = av0;
    *(uint4*)&As[srow * 40 + scol + 8] = av1;
    *(uint4*)&Bs[srow * 40 + scol]     = bv0;
    *(uint4*)&Bs[srow * 40 + scol + 8] = bv1;
    __syncthreads();
    bf16x8 afr[4], bfr[4];
    #pragma unroll
    for (int mt = 0; mt < 4; mt++)
      afr[mt] = *(bf16x8*)&As[(wr * 64 + mt * 16 + (lane & 15)) * 40 + ((lane >> 4) << 3)];
    #pragma unroll
    for (int nt = 0; nt < 4; nt++)
      bfr[nt] = *(bf16x8*)&Bs[(wc * 64 + nt * 16 + (lane & 15)) * 40 + ((lane >> 4) << 3)];
    #pragma unroll
    for (int mt = 0; mt < 4; mt++)
      #pragma unroll
      for (int nt = 0; nt < 4; nt++)
        acc[mt][nt] = __builtin_amdgcn_mfma_f32_16x16x32_bf16(afr[mt], bfr[nt], acc[mt][nt], 0, 0, 0);
    __syncthreads();
  }

  #pragma unroll
  for (int mt = 0; mt < 4; mt++){
    #pragma unroll
    for (int nt = 0; nt < 4; nt++){
      int o = n0 + wc * 64 + nt * 16 + (lane & 15);
      int mb = m0 + wr * 64 + mt * 16 + ((lane >> 4) << 2);
      if (MODE == 0){
        int which = o >> 9, c = o & 511;
        int h = c >> 6, d = c & 63;
        int b = mb >> 10, n = mb & 1023;
        if (which == 2){
          // V: write transposed + slot-permuted: Vt[bh][d][n']
          float bias = b2[c];
          int nperm = (n & ~31) + (((n >> 2) & 3) << 3) + (((n >> 4) & 1) << 2);
          us4 pk;
          #pragma unroll
          for (int j = 0; j < 4; j++) pk[j] = f2b(acc[mt][nt][j] + bias);
          *(us4*)&outV[(((size_t)(b * 8 + h)) << 16) + ((size_t)d << 10) + nperm] = pk;
        } else {
          float bias = (which == 0) ? b0[c] : b1[c];
          u16* base = (which == 0) ? outQ : outK;
          #pragma unroll
          for (int j = 0; j < 4; j++)
            base[(((size_t)(b * 8 + h)) << 16) + ((size_t)(n + j) << 6) + d] = f2b(acc[mt][nt][j] + bias);
        }
      } else {
        float bias = b0[o];
        #pragma unroll
        for (int j = 0; j < 4; j++)
          outF[((size_t)(mb + j) << 9) + o] = acc[mt][nt][j] + bias;
      }
    }
  }
}

// ------------------------------------------------------------------
// 8) flash attention, swapped-operand form.
//    S^T = mfma(K,Q): lane holds 16 scores of q=lane&15 (keys mt*16+4g+j)
//    O^T = mfma(Vt,P): P stays in registers (slot-permuted Vt matches)
// ------------------------------------------------------------------
__global__ __launch_bounds__(256) void k_flash(const u16* __restrict__ Q, const u16* __restrict__ K,
    const u16* __restrict__ Vt, const float* __restrict__ bneg, u16* __restrict__ attnB){
  __shared__ u16 Ks[64 * 72];
  __shared__ u16 Vts[64 * 72];
  __shared__ float mks[64];
  int bid = blockIdx.x;                          // 1024 = bh*16 + qt
  int bh = bid >> 4, q0 = (bid & 15) << 6;
  int t = threadIdx.x, lane = t & 63, w = t >> 6;
  int g = lane >> 4, li = lane & 15;

  const u16* Kp = K  + ((size_t)bh << 16);
  const u16* Vp = Vt + ((size_t)bh << 16);
  const float* bp = bneg + ((size_t)bh << 10);

  // Q fragments in registers (this wave's 16 q-rows; lane owns q = li)
  bf16x8 qfr0, qfr1;
  {
    const u16* qrow = Q + ((size_t)bh << 16) + ((size_t)(q0 + w * 16 + li) << 6);
    qfr0 = *(const bf16x8*)(qrow + g * 8);
    qfr1 = *(const bf16x8*)(qrow + 32 + g * 8);
  }
  float bnq = bp[q0 + w * 16 + li];   // 0 if q unmasked, -1e9 if masked

  f32x4 oacc[4];
  #pragma unroll
  for (int dt = 0; dt < 4; dt++) oacc[dt] = (f32x4){0.f, 0.f, 0.f, 0.f};
  float mrun = -INFINITY, lrun = 0.0f;

  int sr = t >> 2, sc = (t & 3) << 4;
  const u16* kg = Kp + ((size_t)sr << 6) + sc;     // + kt*4096
  const u16* vg = Vp + ((size_t)sr << 10) + sc;    // + kt*64
  uint4 kr0, kr1, vr0, vr1;
  float mr = 0.0f;
  kr0 = *(const uint4*)(kg);
  kr1 = *(const uint4*)(kg + 8);
  vr0 = *(const uint4*)(vg);
  vr1 = *(const uint4*)(vg + 8);
  if (t < 64) mr = bp[t];

  for (int kt = 0; kt < 16; kt++){
    __syncthreads();
    *(uint4*)&Ks[sr * 72 + sc]      = kr0;
    *(uint4*)&Ks[sr * 72 + sc + 8]  = kr1;
    *(uint4*)&Vts[sr * 72 + sc]     = vr0;
    *(uint4*)&Vts[sr * 72 + sc + 8] = vr1;
    if (t < 64) mks[t] = mr;
    if (kt < 15){
      kr0 = *(const uint4*)(kg + (kt + 1) * 4096);
      kr1 = *(const uint4*)(kg + (kt + 1) * 4096 + 8);
      vr0 = *(const uint4*)(vg + (kt + 1) * 64);
      vr1 = *(const uint4*)(vg + (kt + 1) * 64 + 8);
      if (t < 64) mr = bp[(kt + 1) * 64 + t];
    }
    __syncthreads();

    // S^T = K Q^T : sacc[mt][j] = S[key=mt*16+4g+j][q=li]
    f32x4 sacc[4];
    #pragma unroll
    for (int mt = 0; mt < 4; mt++) sacc[mt] = (f32x4){0.f, 0.f, 0.f, 0.f};
    #pragma unroll
    for (int mt = 0; mt < 4; mt++){
      bf16x8 kfr0 = *(bf16x8*)&Ks[(mt * 16 + li) * 72 + g * 8];
      bf16x8 kfr1 = *(bf16x8*)&Ks[(mt * 16 + li) * 72 + 32 + g * 8];
      sacc[mt] = __builtin_amdgcn_mfma_f32_16x16x32_bf16(kfr0, qfr0, sacc[mt], 0, 0, 0);
      sacc[mt] = __builtin_amdgcn_mfma_f32_16x16x32_bf16(kfr1, qfr1, sacc[mt], 0, 0, 0);
    }

    // bias (exact f32 add, matching reference quantization) + row max
    float tmax = -INFINITY;
    #pragma unroll
    for (int mt = 0; mt < 4; mt++){
      float4 bk = *(const float4*)&mks[mt * 16 + g * 4];
      float bkk[4] = {bk.x, bk.y, bk.z, bk.w};
      #pragma unroll
      for (int j = 0; j < 4; j++){
        float s = sacc[mt][j] * 0.125f + fminf(bkk[j], bnq);
        sacc[mt][j] = s;
        tmax = fmaxf(tmax, s);
      }
    }
    tmax = fmaxf(tmax, __shfl_xor(tmax, 16, 64));
    tmax = fmaxf(tmax, __shfl_xor(tmax, 32, 64));
    float mnew = fmaxf(mrun, tmax);
    float scl = __expf(mrun - mnew);
    mrun = mnew;

    float rsum = 0.0f;
    #pragma unroll
    for (int mt = 0; mt < 4; mt++)
      #pragma unroll
      for (int j = 0; j < 4; j++){
        float p = __expf(sacc[mt][j] - mnew);
        sacc[mt][j] = p;
        rsum += p;
      }
    rsum += __shfl_xor(rsum, 16, 64);
    rsum += __shfl_xor(rsum, 32, 64);
    lrun = lrun * scl + rsum;
    #pragma unroll
    for (int dt = 0; dt < 4; dt++)
      #pragma unroll
      for (int j = 0; j < 4; j++) oacc[dt][j] *= scl;

    // P fragments in-register (slot s=g*8+e <-> key 16*(e>=4)+4g+(e&3))
    bf16x8 pfr0, pfr1;
    #pragma unroll
    for (int e = 0; e < 4; e++){
      pfr0[e]     = (short)f2b(sacc[0][e]);
      pfr0[4 + e] = (short)f2b(sacc[1][e]);
      pfr1[e]     = (short)f2b(sacc[2][e]);
      pfr1[4 + e] = (short)f2b(sacc[3][e]);
    }
    // O^T += Vt P : oacc[dt][j] = O[q=li][d=dt*16+4g+j]
    #pragma unroll
    for (int dt = 0; dt < 4; dt++){
      bf16x8 vfr0 = *(bf16x8*)&Vts[(dt * 16 + li) * 72 + g * 8];
      bf16x8 vfr1 = *(bf16x8*)&Vts[(dt * 16 + li) * 72 + 32 + g * 8];
      oacc[dt] = __builtin_amdgcn_mfma_f32_16x16x32_bf16(vfr0, pfr0, oacc[dt], 0, 0, 0);
      oacc[dt] = __builtin_amdgcn_mfma_f32_16x16x32_bf16(vfr1, pfr1, oacc[dt], 0, 0, 0);
    }
  }

  float inv = 1.0f / lrun;
  int b = bh >> 3, h = bh & 7;
  u16* op = attnB + (((size_t)(b * 1024 + q0 + w * 16 + li)) << 9) + h * 64 + g * 4;
  #pragma unroll
  for (int dt = 0; dt < 4; dt++){
    us4 pk;
    #pragma unroll
    for (int j = 0; j < 4; j++) pk[j] = f2b(oacc[dt][j] * inv);
    *(us4*)(op + dt * 16) = pk;
  }
}

// ------------------------------------------------------------------
// 10) LN over C + transpose to (B,C,N)
// ------------------------------------------------------------------
__global__ __launch_bounds__(256) void k_ln(const u16* __restrict__ xfB, const float* __restrict__ attnO,
    const float* __restrict__ gamma, const float* __restrict__ beta, float* __restrict__ out){
  __shared__ float mu_s[64], rs_s[64];
  __shared__ float tile[64][65];
  int b = blockIdx.x >> 4, n0 = (blockIdx.x & 15) << 6;   // grid 128
  int t = threadIdx.x, w = t >> 6, lane = t & 63;

  for (int r = w * 16; r < w * 16 + 16; r++){
    size_t rb = ((size_t)(b * 1024 + n0 + r)) << 9;
    const float* ap = attnO + rb + lane * 8;
    const u16*  xp = xfB + rb + lane * 8;
    float4 a0 = *(const float4*)ap;
    float4 a1 = *(const float4*)(ap + 4);
    union { uint4 v; u16 u[8]; } xv; xv.v = *(const uint4*)xp;
    float v0 = a0.x + b2f(xv.u[0]), v1 = a0.y + b2f(xv.u[1]);
    float v2 = a0.z + b2f(xv.u[2]), v3 = a0.w + b2f(xv.u[3]);
    float v4 = a1.x + b2f(xv.u[4]), v5 = a1.y + b2f(xv.u[5]);
    float v6 = a1.z + b2f(xv.u[6]), v7 = a1.w + b2f(xv.u[7]);
    float s  = v0 + v1 + v2 + v3 + v4 + v5 + v6 + v7;
    float s2 = v0*v0 + v1*v1 + v2*v2 + v3*v3 + v4*v4 + v5*v5 + v6*v6 + v7*v7;
    #pragma unroll
    for (int o = 32; o > 0; o >>= 1){ s += __shfl_xor(s, o, 64); s2 += __shfl_xor(s2, o, 64); }
    if (lane == 0){
      float mu = s * (1.0f / 512.0f);
      float var = s2 * (1.0f / 512.0f) - mu * mu;
      mu_s[r] = mu;
      rs_s[r] = 1.0f / sqrtf(var + 1e-5f);
    }
  }
  __syncthreads();

  for (int ch = 0; ch < 8; ch++){
    int c0 = ch * 64;
    {
      int r = t >> 2, cp = (t & 3) << 4;
      size_t rb = (((size_t)(b * 1024 + n0 + r)) << 9) + c0 + cp;
      float mu = mu_s[r], rstd = rs_s[r];
      #pragma unroll
      for (int i2 = 0; i2 < 2; i2++){
        float4 a0 = *(const float4*)(attnO + rb + i2 * 8);
        float4 a1 = *(const float4*)(attnO + rb + i2 * 8 + 4);
        union { uint4 v; u16 u[8]; } xv; xv.v = *(const uint4*)(xfB + rb + i2 * 8);
        float vv[8] = { a0.x + b2f(xv.u[0]), a0.y + b2f(xv.u[1]), a0.z + b2f(xv.u[2]), a0.w + b2f(xv.u[3]),
                        a1.x + b2f(xv.u[4]), a1.y + b2f(xv.u[5]), a1.z + b2f(xv.u[6]), a1.w + b2f(xv.u[7]) };
        #pragma unroll
        for (int i = 0; i < 8; i++){
          int c = c0 + cp + i2 * 8 + i;
          tile[r][cp + i2 * 8 + i] = (vv[i] - mu) * rstd * gamma[c] + beta[c];
        }
      }
    }
    __syncthreads();
    {
      int cl = t >> 2, np_ = (t & 3) << 4;
      float* op = out + (((size_t)(b * 512 + c0 + cl)) << 10) + n0 + np_;
      #pragma unroll
      for (int i = 0; i < 16; i += 4){
        float4 vo = { tile[np_ + i][cl], tile[np_ + i + 1][cl], tile[np_ + i + 2][cl], tile[np_ + i + 3][cl] };
        *(float4*)(op + i) = vo;
      }
    }
    __syncthreads();
  }
}

// ------------------------------------------------------------------
extern "C" void kernel_launch(void* const* d_in, const int* in_sizes, int n_in,
                              void* d_out, int out_size, void* d_ws, size_t ws_size,
                              hipStream_t stream){
  (void)in_sizes; (void)n_in; (void)out_size; (void)ws_size;
  const float* x    = (const float*)d_in[0];
  const float* Wq   = (const float*)d_in[1];
  const float* bq   = (const float*)d_in[2];
  const float* Wk   = (const float*)d_in[3];
  const float* bk   = (const float*)d_in[4];
  const float* Wv   = (const float*)d_in[5];
  const float* bv   = (const float*)d_in[6];
  const float* Wo   = (const float*)d_in[7];
  const float* bo   = (const float*)d_in[8];
  const float* Wsp  = (const float*)d_in[9];
  const float* bsp  = (const float*)d_in[10];
  const float* Wse1 = (const float*)d_in[11];
  const float* bse1 = (const float*)d_in[12];
  const float* Wse2 = (const float*)d_in[13];
  const float* bse2 = (const float*)d_in[14];
  const float* gamma= (const float*)d_in[15];
  const float* beta = (const float*)d_in[16];
  float* out = (float*)d_out;

  char* ws = (char*)d_ws;
  size_t off = 0;
  auto alloc = [&](size_t bytes) -> void* {
    void* p = ws + off;
    off += (bytes + 255) & ~(size_t)255;
    return p;
  };
  u16*   WB     = (u16*)  alloc(1536 * 512 * 2);
  u16*   WoB    = (u16*)  alloc(512 * 512 * 2);
  float* pooled = (float*)alloc(4096 * 4);
  float* cw     = (float*)alloc(4096 * 4);
  float* mbuf   = (float*)alloc(65536 * 4);
  float* bneg   = (float*)alloc(65536 * 4);
  u16*   xfB    = (u16*)  alloc((size_t)8192 * 512 * 2);
  u16*   Qb     = (u16*)  alloc(8388608);
  u16*   Kb     = (u16*)  alloc(8388608);
  u16*   VtG    = (u16*)  alloc(8388608);
  u16*   attnB  = (u16*)  alloc(8388608);
  float* attnO  = (float*)Qb;   // alias Q+K (16.78MB) after flash is done

  k_cvt   <<<dim3(1024), dim3(256), 0, stream>>>(Wq, Wk, Wv, Wo, WB, WoB);
  k_pooled<<<dim3(1024), dim3(256), 0, stream>>>(x, pooled);
  k_se    <<<dim3(8),    dim3(256), 0, stream>>>(pooled, Wse1, bse1, Wse2, bse2, cw);
  k_sp    <<<dim3(128),  dim3(256), 0, stream>>>(x, Wsp, bsp, mbuf);
  k_mask  <<<dim3(64),   dim3(64),  0, stream>>>(mbuf, bneg);
  k_xf    <<<dim3(1024), dim3(256), 0, stream>>>(x, cw, xfB);
  k_gemm<0><<<dim3(64, 12), dim3(256), 0, stream>>>(xfB, WB, bq, bk, bv, Qb, Kb, VtG, (float*)nullptr);
  k_flash <<<dim3(1024), dim3(256), 0, stream>>>(Qb, Kb, VtG, bneg, attnB);
  k_gemm<1><<<dim3(64, 4), dim3(256), 0, stream>>>(attnB, WoB, bo, bo, bo, nullptr, nullptr, nullptr, attnO);
  k_ln    <<<dim3(128),  dim3(256), 0, stream>>>(xfB, attnO, gamma, beta, out);
}